// Round 1
// 1662.421 us; speedup vs baseline: 1.0771x; 1.0771x over previous
//
#include <hip/hip_runtime.h>
#include <stdint.h>

#define B_  8
#define S_  8192
#define D_  512
#define NB_ 16
#define M_  (B_*S_)   // 65536 rows

typedef short bf16x8 __attribute__((ext_vector_type(8)));
typedef float f32x4  __attribute__((ext_vector_type(4)));

static __device__ __forceinline__ unsigned short f2bf(float f) {
  unsigned int u = __float_as_uint(f);
  u += 0x7fff + ((u >> 16) & 1);   // RNE
  return (unsigned short)(u >> 16);
}

// async global->LDS, 16B per lane. LDS dest is wave-uniform base + lane*16.
static __device__ __forceinline__ void async_copy16(const unsigned short* g,
                                                    unsigned short* l) {
  auto* g1 = reinterpret_cast<const __attribute__((address_space(1))) uint32_t*>(
      reinterpret_cast<uintptr_t>(g));
  auto* l3 = reinterpret_cast<__attribute__((address_space(3))) uint32_t*>(
      reinterpret_cast<uintptr_t>(l));
  __builtin_amdgcn_global_load_lds(g1, l3, 16, 0, 0);
}

__global__ __launch_bounds__(256) void zero_kernel(float* p, int n) {
  int i = blockIdx.x * 256 + threadIdx.x;
  if (i < n) p[i] = 0.f;
}

// Column mean accumulate: acc[b*D+d] += sum_{s in block chunk} x[b][s][d]
__global__ __launch_bounds__(512) void colmean_kernel(const float* __restrict__ x,
                                                      float* __restrict__ acc) {
  int b = blockIdx.x, d = threadIdx.x;
  const float* p = x + ((size_t)b * S_ + (size_t)blockIdx.y * 512) * D_ + d;
  float s = 0.f;
  #pragma unroll 8
  for (int i = 0; i < 512; i++) s += p[(size_t)i * D_];
  atomicAdd(&acc[b * D_ + d], s);
}

// wave0: embodied selector, wave1: disembodied. out[0..1]=emb top2, out[2..3]=dis top2
__global__ __launch_bounds__(128) void top2_kernel(const float* __restrict__ embAcc,
                                                   const float* __restrict__ embW,
                                                   const float* __restrict__ embB,
                                                   const float* __restrict__ disAcc,
                                                   const float* __restrict__ disW,
                                                   const float* __restrict__ disB,
                                                   int* __restrict__ out) {
  int wave = threadIdx.x >> 6, lane = threadIdx.x & 63;
  const float* acc = wave ? disAcc : embAcc;
  const float* W   = wave ? disW   : embW;
  const float* bb  = wave ? disB   : embB;
  const float invS = 1.f / (float)S_;
  float logit[NB_];
  for (int nb = 0; nb < NB_; nb++) {
    float s = 0.f;
    for (int d = lane; d < D_; d += 64) s += acc[d] * invS * W[d * NB_ + nb];
    for (int o = 32; o; o >>= 1) s += __shfl_xor(s, o);
    logit[nb] = s + bb[nb];
  }
  if (lane == 0) {
    int i0 = 0;
    for (int i = 1; i < NB_; i++) if (logit[i] > logit[i0]) i0 = i;
    int i1 = (i0 == 0) ? 1 : 0;
    for (int i = 0; i < NB_; i++) if (i != i0 && logit[i] > logit[i1]) i1 = i;
    out[wave * 2 + 0] = i0;
    out[wave * 2 + 1] = i1;
  }
}

// LayerNorm (dynamic block idx for gamma/beta) + cast to bf16. One wave per row.
__global__ __launch_bounds__(256) void ln_cast_kernel(const float* __restrict__ x,
                                                      const float* __restrict__ gB,
                                                      const float* __restrict__ bB,
                                                      const int* __restrict__ idxPtr,
                                                      unsigned short* __restrict__ out) {
  int row  = blockIdx.x * 4 + (threadIdx.x >> 6);
  int lane = threadIdx.x & 63;
  const float4* xr = (const float4*)(x + (size_t)row * D_ + lane * 8);
  float4 v0 = xr[0], v1 = xr[1];
  float s  = v0.x + v0.y + v0.z + v0.w + v1.x + v1.y + v1.z + v1.w;
  float sq = v0.x*v0.x + v0.y*v0.y + v0.z*v0.z + v0.w*v0.w
           + v1.x*v1.x + v1.y*v1.y + v1.z*v1.z + v1.w*v1.w;
  for (int o = 32; o; o >>= 1) { s += __shfl_xor(s, o); sq += __shfl_xor(sq, o); }
  float mean = s * (1.f / D_);
  float var  = sq * (1.f / D_) - mean * mean;
  float rstd = rsqrtf(var + 1e-5f);
  int idx = *idxPtr;
  const float4* g4 = (const float4*)(gB + (size_t)idx * D_ + lane * 8);
  const float4* b4 = (const float4*)(bB + (size_t)idx * D_ + lane * 8);
  float4 g0 = g4[0], g1 = g4[1], c0 = b4[0], c1 = b4[1];
  float xv[8] = {v0.x, v0.y, v0.z, v0.w, v1.x, v1.y, v1.z, v1.w};
  float gv[8] = {g0.x, g0.y, g0.z, g0.w, g1.x, g1.y, g1.z, g1.w};
  float bv[8] = {c0.x, c0.y, c0.z, c0.w, c1.x, c1.y, c1.z, c1.w};
  unsigned short o8[8] __attribute__((aligned(16)));
  #pragma unroll
  for (int k = 0; k < 8; k++) o8[k] = f2bf((xv[k] - mean) * rstd * gv[k] + bv[k]);
  *(uint4*)(out + (size_t)row * D_ + lane * 8) = *(const uint4*)o8;
}

// Gather selected block's weight [K,N] f32 -> transposed bf16 dst[N][K] (LDS tiled)
__global__ __launch_bounds__(256) void wconvert_kernel(const float* __restrict__ srcAll,
                                                       const int* __restrict__ idxPtr,
                                                       int K, int N,
                                                       unsigned short* __restrict__ dst) {
  __shared__ float t[32][33];
  int idx = *idxPtr;
  const float* src = srcAll + (size_t)idx * K * N;
  int k0 = blockIdx.y * 32, n0 = blockIdx.x * 32;
  int tid = threadIdx.x;
  int kl = tid >> 5, nl = tid & 31;  // kl in 0..7
  #pragma unroll
  for (int r = 0; r < 4; r++)
    t[kl + r * 8][nl] = src[(size_t)(k0 + kl + r * 8) * N + n0 + nl];
  __syncthreads();
  #pragma unroll
  for (int r = 0; r < 4; r++)
    dst[(size_t)(n0 + kl + r * 8) * K + k0 + nl] = f2bf(t[nl][kl + r * 8]);
}

// ---------------------------------------------------------------------------
// R1 rewrite: C[M,N] = A[M,K](bf16) @ Bt[N,K](bf16)^T, fused epilogues.
// 256x256 tile, BK=32, 8 waves (2Mx4N, per-wave 128x64 output, acc 8x4 f32x4).
// 4-deep LDS ring (4 x (A 16KB + B 16KB) = 128 KiB): tile k+3 staged during
// iter k via global_load_lds; ONE counted s_waitcnt vmcnt(10) per K-tile
// (never 0 in-loop -> 3 K-tiles stay in flight across barriers), raw s_barrier
// (2 per K-tile), s_setprio(1) around MFMA clusters (T3+T4+T5).
// BK=32 => 64-B LDS rows => fragment ds_read_b128 are bank-balanced without
// swizzle (the 16-way conflict pattern needs 128-B rows), so staging stays
// linear and global_load_lds-direct.
// EPI 0: bout = bf16(tanh(acc+bias))                         (emb gemm1)
// EPI 1: fout = hin + (acc+bias)*(1+0.1*torsion)*0.3         (emb gemm2)
// EPI 2: fout = hin + 0.5*((acc+bias+0.2*delayed)*(1+0.05*torsion))  (dis attn)
// EPI 3: bout = bf16(gelu_exact(acc+bias))                   (dis ff1)
// EPI 4: fout = hin + 0.5*(acc+bias)                         (dis ff2)
template<int EPI>
__global__ __launch_bounds__(512, 2) void gemm_kernel(const unsigned short* __restrict__ A,
                                                      const unsigned short* __restrict__ Bt,
                                                      int K, int N,
                                                      const int* __restrict__ idxPtr,
                                                      const float* __restrict__ biasBase,
                                                      const float* __restrict__ hin,
                                                      float* __restrict__ fout,
                                                      unsigned short* __restrict__ bout,
                                                      const float* __restrict__ torsion,
                                                      const float* __restrict__ dAcc) {
  __shared__ __align__(16) unsigned short lds[4][2][8192];  // [buf][A|B][256 rows x 32 cols]
  const int tid  = threadIdx.x;
  const int wid  = tid >> 6, lane = tid & 63;
  const int quad = lane >> 4, l16 = lane & 15;
  const int wr = wid >> 2, wc = wid & 3;        // wave -> (2M x 4N) sub-tile

  // XCD-aware tile swizzle (grid is 512 or 1024, both %8==0): XCD x owns a
  // contiguous tile range so neighboring tiles share A rows in its L2.
  const int nT  = N >> 8;                        // 2 or 4 n-tiles
  const int lgn = (nT == 2) ? 1 : 2;
  const int perX = gridDim.x >> 3;
  const int tile = ((int)blockIdx.x & 7) * perX + ((int)blockIdx.x >> 3);
  const int m0 = (tile >> lgn) << 8;
  const int n0 = (tile & (nT - 1)) << 8;

  // staging: thread t covers 16B = row t/4 (per 128-row half), col (t&3)*8
  const int srow = tid >> 2;
  const int scol = (tid & 3) * 8;
  const unsigned short* Ag0 = A  + (size_t)(m0 + srow) * K + scol;
  const unsigned short* Ag1 = Ag0 + (size_t)128 * K;
  const unsigned short* Bg0 = Bt + (size_t)(n0 + srow) * K + scol;
  const unsigned short* Bg1 = Bg0 + (size_t)128 * K;

  auto stageA = [&](int kt, int b) {
    async_copy16(Ag0 + (size_t)kt * 32, &lds[b][0][tid * 8]);
    async_copy16(Ag1 + (size_t)kt * 32, &lds[b][0][4096 + tid * 8]);
  };
  auto stageB = [&](int kt, int b) {
    async_copy16(Bg0 + (size_t)kt * 32, &lds[b][1][tid * 8]);
    async_copy16(Bg1 + (size_t)kt * 32, &lds[b][1][4096 + tid * 8]);
  };

  f32x4 acc[8][4] = {};
  const int nK = K >> 5;

  // prologue: fill ring with tiles 0,1,2 (12 vmcnt items/wave)
  stageA(0, 0); stageB(0, 0);
  stageA(1, 1); stageB(1, 1);
  stageA(2, 2); stageB(2, 2);

  const int aoff = (wr * 128 + l16) * 32 + quad * 8;   // element offsets in LDS
  const int boff = (wc * 64  + l16) * 32 + quad * 8;

  for (int k = 0; k < nK; ++k) {
    const int cur = k & 3;
    const int nxt = (k + 3) & 3;
    const int kn  = (k + 3 < nK) ? (k + 3) : 0;        // clamp keeps vmcnt counts uniform
    stageA(kn, nxt);
    // outstanding newer than tile k: tile k+1 (4) + tile k+2 (4) + A(k+3) (2) = 10
    asm volatile("s_waitcnt vmcnt(10)" ::: "memory");
    asm volatile("s_barrier" ::: "memory");            // tile k visible to all waves

    const unsigned short* Ab = &lds[cur][0][aoff];
    const unsigned short* Bb = &lds[cur][1][boff];
    bf16x8 af[4], bfr[4];
    #pragma unroll
    for (int i = 0; i < 4; ++i) af[i]  = *(const bf16x8*)(Ab + i * 512);      // m-frags 0..3
    #pragma unroll
    for (int j = 0; j < 4; ++j) bfr[j] = *(const bf16x8*)(Bb + j * 512);      // n-frags 0..3
    __builtin_amdgcn_s_setprio(1);
    #pragma unroll
    for (int i = 0; i < 4; ++i)
      #pragma unroll
      for (int j = 0; j < 4; ++j)
        acc[i][j] = __builtin_amdgcn_mfma_f32_16x16x32_bf16(af[i], bfr[j], acc[i][j], 0, 0, 0);
    __builtin_amdgcn_s_setprio(0);

    stageB(kn, nxt);
    #pragma unroll
    for (int i = 0; i < 4; ++i) af[i] = *(const bf16x8*)(Ab + (64 + i * 16) * 32);  // m-frags 4..7
    __builtin_amdgcn_s_setprio(1);
    #pragma unroll
    for (int i = 0; i < 4; ++i)
      #pragma unroll
      for (int j = 0; j < 4; ++j)
        acc[4 + i][j] = __builtin_amdgcn_mfma_f32_16x16x32_bf16(af[i], bfr[j], acc[4 + i][j], 0, 0, 0);
    __builtin_amdgcn_s_setprio(0);
    // all reads of buf[cur] done -> next iter may stage into it
    asm volatile("s_barrier" ::: "memory");
  }

  const int idx = *idxPtr;
  const float* bias = biasBase + (size_t)idx * N;
  const float invS = 1.f / (float)S_;
  #pragma unroll
  for (int mf = 0; mf < 8; ++mf) {
    int rowb = m0 + wr * 128 + mf * 16 + quad * 4;
    #pragma unroll
    for (int nf = 0; nf < 4; ++nf) {
      int col = n0 + wc * 64 + nf * 16 + l16;
      float bc = bias[col];
      #pragma unroll
      for (int r = 0; r < 4; ++r) {
        int row = rowb + r;
        size_t off = (size_t)row * N + col;
        float v = acc[mf][nf][r] + bc;
        if constexpr (EPI == 0) {
          bout[off] = f2bf(tanhf(v));
        } else if constexpr (EPI == 1) {
          int b = row >> 13;  // S = 8192
          float t = 1.f + 0.1f * torsion[b * D_ + col];
          fout[off] = hin[off] + v * t * 0.3f;
        } else if constexpr (EPI == 2) {
          int b = row >> 13;
          float t = 1.f + 0.05f * torsion[b * D_ + col];
          float h1 = (v + 0.2f * dAcc[b * D_ + col] * invS) * t;
          fout[off] = hin[off] + 0.5f * h1;
        } else if constexpr (EPI == 3) {
          float gl = 0.5f * v * (1.f + erff(v * 0.70710678118654752f));
          bout[off] = f2bf(gl);
        } else {
          fout[off] = hin[off] + 0.5f * v;
        }
      }
    }
  }
  asm volatile("s_waitcnt vmcnt(0)" ::: "memory");  // drain stray ring prefetches
}

extern "C" void kernel_launch(void* const* d_in, const int* in_sizes, int n_in,
                              void* d_out, int out_size, void* d_ws, size_t ws_size,
                              hipStream_t stream) {
  const float* emb_input  = (const float*)d_in[0];
  const float* dis_input  = (const float*)d_in[1];
  const float* torsion    = (const float*)d_in[2];
  const float* emb_sel_W  = (const float*)d_in[5];
  const float* emb_sel_b  = (const float*)d_in[6];
  const float* emb_ln_g   = (const float*)d_in[7];
  const float* emb_ln_b   = (const float*)d_in[8];
  const float* emb_w1     = (const float*)d_in[9];
  const float* emb_b1     = (const float*)d_in[10];
  const float* emb_w2     = (const float*)d_in[11];
  const float* emb_b2     = (const float*)d_in[12];
  const float* dis_sel_W  = (const float*)d_in[13];
  const float* dis_sel_b  = (const float*)d_in[14];
  const float* dis_ln1_g  = (const float*)d_in[15];
  const float* dis_ln1_b  = (const float*)d_in[16];
  const float* dis_attn_W = (const float*)d_in[17];
  const float* dis_attn_b = (const float*)d_in[18];
  const float* dis_ln2_g  = (const float*)d_in[19];
  const float* dis_ln2_b  = (const float*)d_in[20];
  const float* dis_ff1_W  = (const float*)d_in[21];
  const float* dis_ff1_b  = (const float*)d_in[22];
  const float* dis_ff2_W  = (const float*)d_in[23];
  const float* dis_ff2_b  = (const float*)d_in[24];

  // workspace carve (needs ~138 MB)
  char* w = (char*)d_ws;
  float* accE = (float*)w;                 // 16 KB  (B*D sums, only b=0 used)
  float* accD = (float*)(w + 16384);       // 16 KB
  int*   top  = (int*)(w + 32768);         // [embTop0, embTop1, disTop0, disTop1]
  size_t o = 33024;
  unsigned short* w1t   = (unsigned short*)(w + o); o += 524288;   // [512][512] bf16
  unsigned short* w2t   = (unsigned short*)(w + o); o += 524288;
  unsigned short* attnT = (unsigned short*)(w + o); o += 524288;
  unsigned short* ff1T  = (unsigned short*)(w + o); o += 1048576;  // [1024][512]
  unsigned short* ff2T  = (unsigned short*)(w + o); o += 1048576;  // [512][1024]
  unsigned short* Abuf  = (unsigned short*)(w + o); o += (size_t)M_ * D_ * 2;  // 67 MB
  unsigned short* T1    = (unsigned short*)(w + o); o += (size_t)M_ * D_ * 2;  // 67 MB

  float* outEmb = (float*)d_out;
  float* outDis = outEmb + (size_t)M_ * D_;
  // dis branch runs FIRST: emb half of d_out doubles as the [M,1024] bf16 gelu buffer
  unsigned short* Gbuf = (unsigned short*)d_out;

  zero_kernel<<<32, 256, 0, stream>>>(accE, 2 * B_ * D_);
  colmean_kernel<<<dim3(1, 16), 512, 0, stream>>>(emb_input, accE);  // only b=0 needed
  colmean_kernel<<<dim3(8, 16), 512, 0, stream>>>(dis_input, accD);
  top2_kernel<<<1, 128, 0, stream>>>(accE, emb_sel_W, emb_sel_b,
                                     accD, dis_sel_W, dis_sel_b, top);

  // ---- disembodied branch (2 selected blocks, sequential)
  for (int s = 0; s < 2; s++) {
    const int* di = top + 2 + s;
    const float* dh = (s == 0) ? dis_input : outDis;
    wconvert_kernel<<<dim3(16, 16), 256, 0, stream>>>(dis_attn_W, di, 512, 512, attnT);
    wconvert_kernel<<<dim3(32, 16), 256, 0, stream>>>(dis_ff1_W,  di, 512, 1024, ff1T);
    wconvert_kernel<<<dim3(16, 32), 256, 0, stream>>>(dis_ff2_W,  di, 1024, 512, ff2T);
    ln_cast_kernel<<<M_ / 4, 256, 0, stream>>>(dh, dis_ln1_g, dis_ln1_b, di, Abuf);
    gemm_kernel<2><<<512, 512, 0, stream>>>(Abuf, attnT, 512, 512, di,
        dis_attn_b, dh, outDis, nullptr, torsion, accD);
    ln_cast_kernel<<<M_ / 4, 256, 0, stream>>>(outDis, dis_ln2_g, dis_ln2_b, di, Abuf);
    gemm_kernel<3><<<1024, 512, 0, stream>>>(Abuf, ff1T, 512, 1024, di,
        dis_ff1_b, nullptr, nullptr, Gbuf, nullptr, nullptr);
    gemm_kernel<4><<<512, 512, 0, stream>>>(Gbuf, ff2T, 1024, 512, di,
        dis_ff2_b, outDis, outDis, nullptr, nullptr, nullptr);
  }

  // ---- embodied branch (overwrites emb half of d_out, which is now free)
  for (int s = 0; s < 2; s++) {
    const int* ei = top + s;
    const float* h = (s == 0) ? emb_input : outEmb;
    wconvert_kernel<<<dim3(16, 16), 256, 0, stream>>>(emb_w1, ei, 512, 512, w1t);
    wconvert_kernel<<<dim3(16, 16), 256, 0, stream>>>(emb_w2, ei, 512, 512, w2t);
    ln_cast_kernel<<<M_ / 4, 256, 0, stream>>>(h, emb_ln_g, emb_ln_b, ei, Abuf);
    gemm_kernel<0><<<512, 512, 0, stream>>>(Abuf, w1t, 512, 512, ei,
        emb_b1, nullptr, nullptr, T1, nullptr, nullptr);
    gemm_kernel<1><<<512, 512, 0, stream>>>(T1, w2t, 512, 512, ei,
        emb_b2, h, outEmb, nullptr, torsion, nullptr);
  }
}

// Round 2
// 1638.476 us; speedup vs baseline: 1.0928x; 1.0146x over previous
//
#include <hip/hip_runtime.h>
#include <stdint.h>

#define B_  8
#define S_  8192
#define D_  512
#define NB_ 16
#define M_  (B_*S_)   // 65536 rows

typedef short bf16x8 __attribute__((ext_vector_type(8)));
typedef float f32x4  __attribute__((ext_vector_type(4)));

static __device__ __forceinline__ unsigned short f2bf(float f) {
  unsigned int u = __float_as_uint(f);
  u += 0x7fff + ((u >> 16) & 1);   // RNE
  return (unsigned short)(u >> 16);
}

// async global->LDS, 16B per lane. LDS dest is wave-uniform base + lane*16.
static __device__ __forceinline__ void async_copy16(const unsigned short* g,
                                                    unsigned short* l) {
  auto* g1 = reinterpret_cast<const __attribute__((address_space(1))) uint32_t*>(
      reinterpret_cast<uintptr_t>(g));
  auto* l3 = reinterpret_cast<__attribute__((address_space(3))) uint32_t*>(
      reinterpret_cast<uintptr_t>(l));
  __builtin_amdgcn_global_load_lds(g1, l3, 16, 0, 0);
}

__global__ __launch_bounds__(256) void zero_kernel(float* p, int n) {
  int i = blockIdx.x * 256 + threadIdx.x;
  if (i < n) p[i] = 0.f;
}

// Column mean accumulate: acc[b*D+d] += sum_{s in block chunk} x[b][s][d]
__global__ __launch_bounds__(512) void colmean_kernel(const float* __restrict__ x,
                                                      float* __restrict__ acc) {
  int b = blockIdx.x, d = threadIdx.x;
  const float* p = x + ((size_t)b * S_ + (size_t)blockIdx.y * 512) * D_ + d;
  float s = 0.f;
  #pragma unroll 8
  for (int i = 0; i < 512; i++) s += p[(size_t)i * D_];
  atomicAdd(&acc[b * D_ + d], s);
}

// wave0: embodied selector, wave1: disembodied. out[0..1]=emb top2, out[2..3]=dis top2
__global__ __launch_bounds__(128) void top2_kernel(const float* __restrict__ embAcc,
                                                   const float* __restrict__ embW,
                                                   const float* __restrict__ embB,
                                                   const float* __restrict__ disAcc,
                                                   const float* __restrict__ disW,
                                                   const float* __restrict__ disB,
                                                   int* __restrict__ out) {
  int wave = threadIdx.x >> 6, lane = threadIdx.x & 63;
  const float* acc = wave ? disAcc : embAcc;
  const float* W   = wave ? disW   : embW;
  const float* bb  = wave ? disB   : embB;
  const float invS = 1.f / (float)S_;
  float logit[NB_];
  for (int nb = 0; nb < NB_; nb++) {
    float s = 0.f;
    for (int d = lane; d < D_; d += 64) s += acc[d] * invS * W[d * NB_ + nb];
    for (int o = 32; o; o >>= 1) s += __shfl_xor(s, o);
    logit[nb] = s + bb[nb];
  }
  if (lane == 0) {
    int i0 = 0;
    for (int i = 1; i < NB_; i++) if (logit[i] > logit[i0]) i0 = i;
    int i1 = (i0 == 0) ? 1 : 0;
    for (int i = 0; i < NB_; i++) if (i != i0 && logit[i] > logit[i1]) i1 = i;
    out[wave * 2 + 0] = i0;
    out[wave * 2 + 1] = i1;
  }
}

// LayerNorm (dynamic block idx for gamma/beta) + cast to bf16. One wave per row.
__global__ __launch_bounds__(256) void ln_cast_kernel(const float* __restrict__ x,
                                                      const float* __restrict__ gB,
                                                      const float* __restrict__ bB,
                                                      const int* __restrict__ idxPtr,
                                                      unsigned short* __restrict__ out) {
  int row  = blockIdx.x * 4 + (threadIdx.x >> 6);
  int lane = threadIdx.x & 63;
  const float4* xr = (const float4*)(x + (size_t)row * D_ + lane * 8);
  float4 v0 = xr[0], v1 = xr[1];
  float s  = v0.x + v0.y + v0.z + v0.w + v1.x + v1.y + v1.z + v1.w;
  float sq = v0.x*v0.x + v0.y*v0.y + v0.z*v0.z + v0.w*v0.w
           + v1.x*v1.x + v1.y*v1.y + v1.z*v1.z + v1.w*v1.w;
  for (int o = 32; o; o >>= 1) { s += __shfl_xor(s, o); sq += __shfl_xor(sq, o); }
  float mean = s * (1.f / D_);
  float var  = sq * (1.f / D_) - mean * mean;
  float rstd = rsqrtf(var + 1e-5f);
  int idx = *idxPtr;
  const float4* g4 = (const float4*)(gB + (size_t)idx * D_ + lane * 8);
  const float4* b4 = (const float4*)(bB + (size_t)idx * D_ + lane * 8);
  float4 g0 = g4[0], g1 = g4[1], c0 = b4[0], c1 = b4[1];
  float xv[8] = {v0.x, v0.y, v0.z, v0.w, v1.x, v1.y, v1.z, v1.w};
  float gv[8] = {g0.x, g0.y, g0.z, g0.w, g1.x, g1.y, g1.z, g1.w};
  float bv[8] = {c0.x, c0.y, c0.z, c0.w, c1.x, c1.y, c1.z, c1.w};
  unsigned short o8[8] __attribute__((aligned(16)));
  #pragma unroll
  for (int k = 0; k < 8; k++) o8[k] = f2bf((xv[k] - mean) * rstd * gv[k] + bv[k]);
  *(uint4*)(out + (size_t)row * D_ + lane * 8) = *(const uint4*)o8;
}

// Gather selected block's weight [K,N] f32 -> transposed bf16 dst[N][K] (LDS tiled)
__global__ __launch_bounds__(256) void wconvert_kernel(const float* __restrict__ srcAll,
                                                       const int* __restrict__ idxPtr,
                                                       int K, int N,
                                                       unsigned short* __restrict__ dst) {
  __shared__ float t[32][33];
  int idx = *idxPtr;
  const float* src = srcAll + (size_t)idx * K * N;
  int k0 = blockIdx.y * 32, n0 = blockIdx.x * 32;
  int tid = threadIdx.x;
  int kl = tid >> 5, nl = tid & 31;  // kl in 0..7
  #pragma unroll
  for (int r = 0; r < 4; r++)
    t[kl + r * 8][nl] = src[(size_t)(k0 + kl + r * 8) * N + n0 + nl];
  __syncthreads();
  #pragma unroll
  for (int r = 0; r < 4; r++)
    dst[(size_t)(n0 + kl + r * 8) * K + k0 + nl] = f2bf(t[nl][kl + r * 8]);
}

// ---------------------------------------------------------------------------
// R2: R1's 256x256 / BK=32 / 8-wave / 4-deep-ring schedule UNCHANGED, plus the
// XOR segment-swizzle the 128^2 baseline had (dropped by mistake in R1):
//   physical 16B slot p of LDS row r holds logical K-segment p ^ ((r>>1)&3).
// Writer: pre-swizzled GLOBAL source per thread (global_load_lds dest stays
// linear, rule #21); reader: slot quad ^ ((l16>>1)&3). Lane addrs mod 128B now
// cover all 8 bank-groups with 2-way aliasing (free, m136) instead of 8-way.
// EPI 0: bout = bf16(tanh(acc+bias))                         (emb gemm1)
// EPI 1: fout = hin + (acc+bias)*(1+0.1*torsion)*0.3         (emb gemm2)
// EPI 2: fout = hin + 0.5*((acc+bias+0.2*delayed)*(1+0.05*torsion))  (dis attn)
// EPI 3: bout = bf16(gelu_exact(acc+bias))                   (dis ff1)
// EPI 4: fout = hin + 0.5*(acc+bias)                         (dis ff2)
template<int EPI>
__global__ __launch_bounds__(512, 2) void gemm_kernel(const unsigned short* __restrict__ A,
                                                      const unsigned short* __restrict__ Bt,
                                                      int K, int N,
                                                      const int* __restrict__ idxPtr,
                                                      const float* __restrict__ biasBase,
                                                      const float* __restrict__ hin,
                                                      float* __restrict__ fout,
                                                      unsigned short* __restrict__ bout,
                                                      const float* __restrict__ torsion,
                                                      const float* __restrict__ dAcc) {
  __shared__ __align__(16) unsigned short lds[4][2][8192];  // [buf][A|B][256 rows x 32 cols]
  const int tid  = threadIdx.x;
  const int wid  = tid >> 6, lane = tid & 63;
  const int quad = lane >> 4, l16 = lane & 15;
  const int wr = wid >> 2, wc = wid & 3;        // wave -> (2M x 4N) sub-tile

  // XCD-aware tile swizzle (grid is 512 or 1024, both %8==0): XCD x owns a
  // contiguous tile range so neighboring tiles share A rows in its L2.
  const int nT  = N >> 8;                        // 2 or 4 n-tiles
  const int lgn = (nT == 2) ? 1 : 2;
  const int perX = gridDim.x >> 3;
  const int tile = ((int)blockIdx.x & 7) * perX + ((int)blockIdx.x >> 3);
  const int m0 = (tile >> lgn) << 8;
  const int n0 = (tile & (nT - 1)) << 8;

  // staging: thread t covers 16B of row t/4 (per 128-row half). HW writes LDS
  // linearly at slot (t&3); fetch logical K-segment (t&3)^sw(row), sw(r)=(r>>1)&3.
  const int srow = tid >> 2;
  const int scol = (((tid & 3) ^ ((tid >> 3) & 3)) * 8);
  const unsigned short* Ag0 = A  + (size_t)(m0 + srow) * K + scol;
  const unsigned short* Ag1 = Ag0 + (size_t)128 * K;
  const unsigned short* Bg0 = Bt + (size_t)(n0 + srow) * K + scol;
  const unsigned short* Bg1 = Bg0 + (size_t)128 * K;

  auto stageA = [&](int kt, int b) {
    async_copy16(Ag0 + (size_t)kt * 32, &lds[b][0][tid * 8]);
    async_copy16(Ag1 + (size_t)kt * 32, &lds[b][0][4096 + tid * 8]);
  };
  auto stageB = [&](int kt, int b) {
    async_copy16(Bg0 + (size_t)kt * 32, &lds[b][1][tid * 8]);
    async_copy16(Bg1 + (size_t)kt * 32, &lds[b][1][4096 + tid * 8]);
  };

  f32x4 acc[8][4] = {};
  const int nK = K >> 5;

  // prologue: fill ring with tiles 0,1,2 (12 vmcnt items/wave)
  stageA(0, 0); stageB(0, 0);
  stageA(1, 1); stageB(1, 1);
  stageA(2, 2); stageB(2, 2);

  // fragment read swizzle: rows used are (multiple of 16 or 64) + l16, and
  // 16|64 leave (r>>1)&3's contribution = 0 mod 4 shifts... concretely
  // sw(base + l16) has base's term (base>>1)&3 = 0 for base in {0,64} mod 8*2;
  // i*16 adds 8 mod 4 = 0. So rsw depends on l16 only.
  const int rsw  = (l16 >> 1) & 3;
  const int aoff = (wr * 128 + l16) * 32 + ((quad ^ rsw) * 8);
  const int boff = (wc * 64  + l16) * 32 + ((quad ^ rsw) * 8);

  for (int k = 0; k < nK; ++k) {
    const int cur = k & 3;
    const int nxt = (k + 3) & 3;
    const int kn  = (k + 3 < nK) ? (k + 3) : 0;        // clamp keeps vmcnt counts uniform
    stageA(kn, nxt);
    // outstanding newer than tile k: tile k+1 (4) + tile k+2 (4) + A(k+3) (2) = 10
    asm volatile("s_waitcnt vmcnt(10)" ::: "memory");
    asm volatile("s_barrier" ::: "memory");            // tile k visible to all waves

    const unsigned short* Ab = &lds[cur][0][aoff];
    const unsigned short* Bb = &lds[cur][1][boff];
    bf16x8 af[4], bfr[4];
    #pragma unroll
    for (int i = 0; i < 4; ++i) af[i]  = *(const bf16x8*)(Ab + i * 512);      // m-frags 0..3
    #pragma unroll
    for (int j = 0; j < 4; ++j) bfr[j] = *(const bf16x8*)(Bb + j * 512);      // n-frags 0..3
    __builtin_amdgcn_s_setprio(1);
    #pragma unroll
    for (int i = 0; i < 4; ++i)
      #pragma unroll
      for (int j = 0; j < 4; ++j)
        acc[i][j] = __builtin_amdgcn_mfma_f32_16x16x32_bf16(af[i], bfr[j], acc[i][j], 0, 0, 0);
    __builtin_amdgcn_s_setprio(0);

    stageB(kn, nxt);
    #pragma unroll
    for (int i = 0; i < 4; ++i) af[i] = *(const bf16x8*)(Ab + (64 + i * 16) * 32);  // m-frags 4..7
    __builtin_amdgcn_s_setprio(1);
    #pragma unroll
    for (int i = 0; i < 4; ++i)
      #pragma unroll
      for (int j = 0; j < 4; ++j)
        acc[4 + i][j] = __builtin_amdgcn_mfma_f32_16x16x32_bf16(af[i], bfr[j], acc[4 + i][j], 0, 0, 0);
    __builtin_amdgcn_s_setprio(0);
    // all reads of buf[cur] done -> next iter may stage into it
    asm volatile("s_barrier" ::: "memory");
  }

  const int idx = *idxPtr;
  const float* bias = biasBase + (size_t)idx * N;
  const float invS = 1.f / (float)S_;
  #pragma unroll
  for (int mf = 0; mf < 8; ++mf) {
    int rowb = m0 + wr * 128 + mf * 16 + quad * 4;
    #pragma unroll
    for (int nf = 0; nf < 4; ++nf) {
      int col = n0 + wc * 64 + nf * 16 + l16;
      float bc = bias[col];
      #pragma unroll
      for (int r = 0; r < 4; ++r) {
        int row = rowb + r;
        size_t off = (size_t)row * N + col;
        float v = acc[mf][nf][r] + bc;
        if constexpr (EPI == 0) {
          bout[off] = f2bf(tanhf(v));
        } else if constexpr (EPI == 1) {
          int b = row >> 13;  // S = 8192
          float t = 1.f + 0.1f * torsion[b * D_ + col];
          fout[off] = hin[off] + v * t * 0.3f;
        } else if constexpr (EPI == 2) {
          int b = row >> 13;
          float t = 1.f + 0.05f * torsion[b * D_ + col];
          float h1 = (v + 0.2f * dAcc[b * D_ + col] * invS) * t;
          fout[off] = hin[off] + 0.5f * h1;
        } else if constexpr (EPI == 3) {
          float gl = 0.5f * v * (1.f + erff(v * 0.70710678118654752f));
          bout[off] = f2bf(gl);
        } else {
          fout[off] = hin[off] + 0.5f * v;
        }
      }
    }
  }
  asm volatile("s_waitcnt vmcnt(0)" ::: "memory");  // drain stray ring prefetches
}

extern "C" void kernel_launch(void* const* d_in, const int* in_sizes, int n_in,
                              void* d_out, int out_size, void* d_ws, size_t ws_size,
                              hipStream_t stream) {
  const float* emb_input  = (const float*)d_in[0];
  const float* dis_input  = (const float*)d_in[1];
  const float* torsion    = (const float*)d_in[2];
  const float* emb_sel_W  = (const float*)d_in[5];
  const float* emb_sel_b  = (const float*)d_in[6];
  const float* emb_ln_g   = (const float*)d_in[7];
  const float* emb_ln_b   = (const float*)d_in[8];
  const float* emb_w1     = (const float*)d_in[9];
  const float* emb_b1     = (const float*)d_in[10];
  const float* emb_w2     = (const float*)d_in[11];
  const float* emb_b2     = (const float*)d_in[12];
  const float* dis_sel_W  = (const float*)d_in[13];
  const float* dis_sel_b  = (const float*)d_in[14];
  const float* dis_ln1_g  = (const float*)d_in[15];
  const float* dis_ln1_b  = (const float*)d_in[16];
  const float* dis_attn_W = (const float*)d_in[17];
  const float* dis_attn_b = (const float*)d_in[18];
  const float* dis_ln2_g  = (const float*)d_in[19];
  const float* dis_ln2_b  = (const float*)d_in[20];
  const float* dis_ff1_W  = (const float*)d_in[21];
  const float* dis_ff1_b  = (const float*)d_in[22];
  const float* dis_ff2_W  = (const float*)d_in[23];
  const float* dis_ff2_b  = (const float*)d_in[24];

  // workspace carve (needs ~138 MB)
  char* w = (char*)d_ws;
  float* accE = (float*)w;                 // 16 KB  (B*D sums, only b=0 used)
  float* accD = (float*)(w + 16384);       // 16 KB
  int*   top  = (int*)(w + 32768);         // [embTop0, embTop1, disTop0, disTop1]
  size_t o = 33024;
  unsigned short* w1t   = (unsigned short*)(w + o); o += 524288;   // [512][512] bf16
  unsigned short* w2t   = (unsigned short*)(w + o); o += 524288;
  unsigned short* attnT = (unsigned short*)(w + o); o += 524288;
  unsigned short* ff1T  = (unsigned short*)(w + o); o += 1048576;  // [1024][512]
  unsigned short* ff2T  = (unsigned short*)(w + o); o += 1048576;  // [512][1024]
  unsigned short* Abuf  = (unsigned short*)(w + o); o += (size_t)M_ * D_ * 2;  // 67 MB
  unsigned short* T1    = (unsigned short*)(w + o); o += (size_t)M_ * D_ * 2;  // 67 MB

  float* outEmb = (float*)d_out;
  float* outDis = outEmb + (size_t)M_ * D_;
  // dis branch runs FIRST: emb half of d_out doubles as the [M,1024] bf16 gelu buffer
  unsigned short* Gbuf = (unsigned short*)d_out;

  zero_kernel<<<32, 256, 0, stream>>>(accE, 2 * B_ * D_);
  colmean_kernel<<<dim3(1, 16), 512, 0, stream>>>(emb_input, accE);  // only b=0 needed
  colmean_kernel<<<dim3(8, 16), 512, 0, stream>>>(dis_input, accD);
  top2_kernel<<<1, 128, 0, stream>>>(accE, emb_sel_W, emb_sel_b,
                                     accD, dis_sel_W, dis_sel_b, top);

  // ---- disembodied branch (2 selected blocks, sequential)
  for (int s = 0; s < 2; s++) {
    const int* di = top + 2 + s;
    const float* dh = (s == 0) ? dis_input : outDis;
    wconvert_kernel<<<dim3(16, 16), 256, 0, stream>>>(dis_attn_W, di, 512, 512, attnT);
    wconvert_kernel<<<dim3(32, 16), 256, 0, stream>>>(dis_ff1_W,  di, 512, 1024, ff1T);
    wconvert_kernel<<<dim3(16, 32), 256, 0, stream>>>(dis_ff2_W,  di, 1024, 512, ff2T);
    ln_cast_kernel<<<M_ / 4, 256, 0, stream>>>(dh, dis_ln1_g, dis_ln1_b, di, Abuf);
    gemm_kernel<2><<<512, 512, 0, stream>>>(Abuf, attnT, 512, 512, di,
        dis_attn_b, dh, outDis, nullptr, torsion, accD);
    ln_cast_kernel<<<M_ / 4, 256, 0, stream>>>(outDis, dis_ln2_g, dis_ln2_b, di, Abuf);
    gemm_kernel<3><<<1024, 512, 0, stream>>>(Abuf, ff1T, 512, 1024, di,
        dis_ff1_b, nullptr, nullptr, Gbuf, nullptr, nullptr);
    gemm_kernel<4><<<512, 512, 0, stream>>>(Gbuf, ff2T, 1024, 512, di,
        dis_ff2_b, outDis, outDis, nullptr, nullptr, nullptr);
  }

  // ---- embodied branch (overwrites emb half of d_out, which is now free)
  for (int s = 0; s < 2; s++) {
    const int* ei = top + s;
    const float* h = (s == 0) ? emb_input : outEmb;
    wconvert_kernel<<<dim3(16, 16), 256, 0, stream>>>(emb_w1, ei, 512, 512, w1t);
    wconvert_kernel<<<dim3(16, 16), 256, 0, stream>>>(emb_w2, ei, 512, 512, w2t);
    ln_cast_kernel<<<M_ / 4, 256, 0, stream>>>(h, emb_ln_g, emb_ln_b, ei, Abuf);
    gemm_kernel<0><<<512, 512, 0, stream>>>(Abuf, w1t, 512, 512, ei,
        emb_b1, nullptr, nullptr, T1, nullptr, nullptr);
    gemm_kernel<1><<<512, 512, 0, stream>>>(T1, w2t, 512, 512, ei,
        emb_b2, h, outEmb, nullptr, torsion, nullptr);
  }
}